// Round 9
// baseline (188.734 us; speedup 1.0000x reference)
//
#include <hip/hip_runtime.h>
#include <hip/hip_bf16.h>
#include <math.h>

// Problem constants (B, CIN, COUT, K, S, P, D) = (4,128,128,3,1,1,1), H=W=96
#define HH 96
#define WW 96
#define HW (96*96)
#define CIN_ 128
#define COUT_ 128
#define OUT_ELEMS (4*128*96*96)

// ws layout (bytes)
#define XT_OFF   0u           // x_t bf16 [4][9216][128] = 9,437,184 B
#define OM_OFF   9437184u     // om raw fp32 [4][27][9216] = 3,981,312 B
#define WBF_OFF  13418496u    // wbf bf16 [128][1152] (q=kc*128+c) = 294,912 B
#define WOMB_OFF 13713408u    // womb bf16 [32][1152] (q=kc*128+c, rows>=27 zero)

#define BT_STRIDE 68          // btile row stride in dwords (16B-aligned rows)

typedef __attribute__((ext_vector_type(8))) short short8v;
typedef __attribute__((ext_vector_type(4))) float float4v;

__device__ __forceinline__ unsigned short f2bf(float f) {
    unsigned u = __builtin_bit_cast(unsigned, f);
    u += 0x7FFFu + ((u >> 16) & 1u);   // RNE (inputs finite)
    return (unsigned short)(u >> 16);
}
__device__ __forceinline__ float bflo(unsigned u) {
    return __builtin_bit_cast(float, u << 16);
}
__device__ __forceinline__ float bfhi(unsigned u) {
    return __builtin_bit_cast(float, u & 0xffff0000u);
}

// ---------------------------------------------------------------------------
// x [4][128][9216] fp32 -> x_t [4][9216][128] bf16, PLUS (blocks 144..147)
// weight fp32->bf16 reorder (q=kc*128+c).  Grid (148,4), 256 thr.
// Weight blocks and transpose blocks touch disjoint memory.
// ---------------------------------------------------------------------------
__global__ __launch_bounds__(256) void transpose_kernel(
    const float* __restrict__ x, const float* __restrict__ w,
    const float* __restrict__ wom, unsigned short* __restrict__ xt,
    unsigned short* __restrict__ wbf, unsigned short* __restrict__ womb)
{
    __shared__ float tile[64][130];
    const int t = threadIdx.x;

    if (blockIdx.x >= 144) {
        // ---- weight conversion: 16 blocks x 256 thr -----------------------
        const int wbk = (blockIdx.x - 144) * 4 + blockIdx.y;   // 0..15
        for (int i = wbk * 256 + t; i < 160 * 1152; i += 16 * 256) {
            if (i < COUT_ * 1152) {
                const int oc = i / 1152, r = i - oc * 1152;
                const int kc = r >> 7, c = r & 127;
                wbf[i] = f2bf(w[(size_t)oc * 1152 + c * 9 + kc]);
            } else {
                const int i2 = i - COUT_ * 1152;
                const int row = i2 / 1152, r = i2 - row * 1152;
                const int kc = r >> 7, c = r & 127;
                womb[i2] = (row < 27) ? f2bf(wom[(size_t)row * 1152 + c * 9 + kc]) : 0;
            }
        }
        return;
    }

    const int b  = blockIdx.y;
    const int p0 = blockIdx.x * 64;

#pragma unroll
    for (int j = 0; j < 8; j++) {               // read: 4 px per thread (float4)
        const int i  = j * 256 + t;
        const int c  = i >> 4;
        const int p4 = (i & 15) * 4;
        const float4 v = *(const float4*)(x + ((size_t)(b * CIN_ + c) * HW + p0 + p4));
        tile[p4 + 0][c] = v.x; tile[p4 + 1][c] = v.y;
        tile[p4 + 2][c] = v.z; tile[p4 + 3][c] = v.w;
    }
    __syncthreads();
#pragma unroll
    for (int j = 0; j < 8; j++) {               // write: 4 c per thread (8 B bf16)
        const int i   = j * 256 + t;
        const int pxl = i >> 5;
        const int c4  = (i & 31) * 4;
        uint2 v;
        v.x = (unsigned)f2bf(tile[pxl][c4 + 0]) | ((unsigned)f2bf(tile[pxl][c4 + 1]) << 16);
        v.y = (unsigned)f2bf(tile[pxl][c4 + 2]) | ((unsigned)f2bf(tile[pxl][c4 + 3]) << 16);
        *(uint2*)(xt + ((size_t)(b * HW + p0 + pxl) * CIN_ + c4)) = v;
    }
}

// ---------------------------------------------------------------------------
// Offset/mask conv as bf16 MFMA GEMM — LDS-free, B-frags double-buffered in
// registers one kc ahead (pure per-thread registers: race-free).
// Grid (144,4), 256 thr.  Wave = 16-px n-tile (wave*16+m), 2 m-tiles.
// ---------------------------------------------------------------------------
__global__ __launch_bounds__(256, 4) void om_gemm_kernel(
    const unsigned short* __restrict__ xt, const unsigned short* __restrict__ womb,
    float* __restrict__ om, float* __restrict__ off_out)
{
    const int t    = threadIdx.x;
    const int wave = __builtin_amdgcn_readfirstlane(t >> 6);
    const int lane = t & 63;
    const int quad = lane >> 4;
    const int m    = lane & 15;
    const int b    = blockIdx.y;
    const int p0   = blockIdx.x * 64;

    const unsigned short* xtb = xt + (size_t)b * HW * CIN_;

    const int pg = p0 + wave * 16 + m;
    const int h  = pg / 96;
    const int w  = pg - h * 96;

    float4v acc[2];
#pragma unroll
    for (int i = 0; i < 2; i++)
#pragma unroll
        for (int r = 0; r < 4; r++) acc[i][r] = 0.f;

    const short8v zerov = (short8v)0;
    short8v bfb[2][4];

    auto loadB = [&](int kc, int buf) {
        const int ki = kc / 3, kj = kc - 3 * (kc / 3);
        const int y  = h + ki - 1, xx = w + kj - 1;
        const bool valid = ((unsigned)y < 96u) && ((unsigned)xx < 96u);
        const unsigned short* brow = xtb + (size_t)(y * 96 + xx) * CIN_ + quad * 8;
#pragma unroll
        for (int kst = 0; kst < 4; kst++)
            bfb[buf][kst] = valid ? *(const short8v*)(brow + kst * 32) : zerov;
    };

    loadB(0, 0);
#pragma unroll
    for (int kc = 0; kc < 9; kc++) {
        if (kc < 8) loadB(kc + 1, (kc + 1) & 1);   // in flight during MFMA below
        const short* abase = (const short*)womb + kc * 128 + quad * 8;
#pragma unroll
        for (int kst = 0; kst < 4; kst++) {
#pragma unroll
            for (int mt = 0; mt < 2; mt++) {
                const short8v a = *(const short8v*)(abase + (size_t)(mt * 16 + m) * 1152 + kst * 32);
                acc[mt] = __builtin_amdgcn_mfma_f32_16x16x32_bf16(a, bfb[kc & 1][kst], acc[mt], 0, 0, 0);
            }
        }
    }

    // epilogue: D col=lane&15 -> px, row=quad*4+r -> oc
#pragma unroll
    for (int mt = 0; mt < 2; mt++) {
#pragma unroll
        for (int r = 0; r < 4; r++) {
            const int oc = mt * 16 + quad * 4 + r;
            const int px = p0 + wave * 16 + m;
            if (oc < 27) om[((size_t)(b * 27 + oc)) * HW + px] = acc[mt][r];
            if (oc < 18) off_out[((size_t)(b * 18 + oc)) * HW + px] = acc[mt][r];
        }
    }
}

// ---------------------------------------------------------------------------
// Main: deformable gather + MFMA GEMM + bias (R6-proven version, verbatim).
// Grid (144,4), 512 thr (8 waves).  Block: 64 px x 128 oc, K=1152 in 9 kc.
// ---------------------------------------------------------------------------
__global__ __launch_bounds__(512, 4) void dconv_kernel(
    const unsigned short* __restrict__ xt, const unsigned short* __restrict__ wbf,
    const float* __restrict__ bias, const float* __restrict__ om,
    float* __restrict__ out)
{
    __shared__ int sprep[576 * 8];          // 18432 B
    __shared__ int btile[64 * BT_STRIDE];   // 17408 B  (total 35840 B)

    const int t    = threadIdx.x;
    const int wave = __builtin_amdgcn_readfirstlane(t >> 6);
    const int lane = t & 63;
    const int quad = lane >> 4;
    const int m    = lane & 15;
    const int b    = blockIdx.y;
    const int p0   = blockIdx.x * 64;

    // ---- phase 1: sampling prep -------------------------------------------
    for (int s = t; s < 576; s += 512) {
        const int kc  = s >> 6;
        const int pxl = s & 63;
        const int pg  = p0 + pxl;
        const int h   = pg / 96;
        const int w   = pg - h * 96;
        const int ki  = kc / 3, kj = kc - 3 * (kc / 3);

        const float* omb = om + (size_t)b * 27 * HW + pg;
        const float o1 = omb[(size_t)kc * HW];
        const float o2 = omb[(size_t)(9 + kc) * HW];
        const float mr = omb[(size_t)(18 + kc) * HW];
        const float mk = 2.f / (1.f + __expf(-mr));   // sigmoid * MASK_SCALE

        const float py = (float)(h - 1 + ki) + o1;
        const float px = (float)(w - 1 + kj) + o2;
        const float y0f = floorf(py), x0f = floorf(px);
        const float ly = py - y0f,    lx = px - x0f;
        const int y0 = (int)y0f, x0 = (int)x0f;
        const int y1 = y0 + 1,   x1 = x0 + 1;

        const float w00 = (1.f - ly) * (1.f - lx), w01 = (1.f - ly) * lx;
        const float w10 = ly * (1.f - lx),         w11 = ly * lx;

        const int yc0 = min(max(y0, 0), HH - 1), yc1 = min(max(y1, 0), HH - 1);
        const int xc0 = min(max(x0, 0), WW - 1), xc1 = min(max(x1, 0), WW - 1);
        const bool vy0 = (y0 >= 0) && (y0 < HH), vy1 = (y1 >= 0) && (y1 < HH);
        const bool vx0 = (x0 >= 0) && (x0 < WW), vx1 = (x1 >= 0) && (x1 < WW);

        sprep[s * 8 + 0] = yc0 * 96 + xc0;
        sprep[s * 8 + 1] = yc0 * 96 + xc1;
        sprep[s * 8 + 2] = yc1 * 96 + xc0;
        sprep[s * 8 + 3] = yc1 * 96 + xc1;
        sprep[s * 8 + 4] = __builtin_bit_cast(int, (vy0 && vx0) ? mk * w00 : 0.f);
        sprep[s * 8 + 5] = __builtin_bit_cast(int, (vy0 && vx1) ? mk * w01 : 0.f);
        sprep[s * 8 + 6] = __builtin_bit_cast(int, (vy1 && vx0) ? mk * w10 : 0.f);
        sprep[s * 8 + 7] = __builtin_bit_cast(int, (vy1 && vx1) ? mk * w11 : 0.f);
    }
    __syncthreads();

    const unsigned short* xtb = xt + (size_t)b * HW * CIN_;

    float4v acc[4];
#pragma unroll
    for (int j = 0; j < 4; j++)
#pragma unroll
        for (int r = 0; r < 4; r++) acc[j][r] = 0.f;

    for (int kc = 0; kc < 9; kc++) {
        if (kc) __syncthreads();

        // ---- gather: wave-per-pixel, lane = 2 channels (bf16 pair = 4 B) --
#pragma unroll
        for (int p = 0; p < 8; p++) {
            const int pxl = p * 8 + wave;
            const int s   = kc * 64 + pxl;
            const int4   id4 = *(const int4*)&sprep[s * 8];
            const float4 w4  = *(const float4*)&sprep[s * 8 + 4];
            const unsigned u0 = *(const unsigned*)(xtb + (size_t)id4.x * CIN_ + 2 * lane);
            const unsigned u1 = *(const unsigned*)(xtb + (size_t)id4.y * CIN_ + 2 * lane);
            const unsigned u2 = *(const unsigned*)(xtb + (size_t)id4.z * CIN_ + 2 * lane);
            const unsigned u3 = *(const unsigned*)(xtb + (size_t)id4.w * CIN_ + 2 * lane);
            const float vx = w4.x * bflo(u0) + w4.y * bflo(u1) + w4.z * bflo(u2) + w4.w * bflo(u3);
            const float vy = w4.x * bfhi(u0) + w4.y * bfhi(u1) + w4.z * bfhi(u2) + w4.w * bfhi(u3);
            btile[pxl * BT_STRIDE + lane] =
                (int)((unsigned)f2bf(vx) | ((unsigned)f2bf(vy) << 16));
        }
        __syncthreads();

        // ---- MFMA: wave = 16-oc slice; 4 kst x 4 nt -----------------------
        const short* abase = (const short*)wbf + (size_t)(wave * 16 + m) * 1152 + kc * 128 + quad * 8;
#pragma unroll
        for (int kst = 0; kst < 4; kst++) {
            const short8v a = *(const short8v*)(abase + kst * 32);
#pragma unroll
            for (int nt = 0; nt < 4; nt++) {
                const short8v bf = *(const short8v*)((const short*)btile
                    + (nt * 16 + m) * (BT_STRIDE * 2) + kst * 32 + quad * 8);
                acc[nt] = __builtin_amdgcn_mfma_f32_16x16x32_bf16(a, bf, acc[nt], 0, 0, 0);
            }
        }
    }

    // ---- epilogue ---------------------------------------------------------
#pragma unroll
    for (int r = 0; r < 4; r++) {
        const int oc = wave * 16 + quad * 4 + r;
        const float bv = bias[oc];
#pragma unroll
        for (int nt = 0; nt < 4; nt++)
            out[(size_t)(b * COUT_ + oc) * HW + p0 + nt * 16 + m] = acc[nt][r] + bv;
    }
}

extern "C" void kernel_launch(void* const* d_in, const int* in_sizes, int n_in,
                              void* d_out, int out_size, void* d_ws, size_t ws_size,
                              hipStream_t stream) {
    const float* x      = (const float*)d_in[0];
    const float* weight = (const float*)d_in[1];
    const float* bias   = (const float*)d_in[2];
    const float* wom    = (const float*)d_in[3];

    float* out     = (float*)d_out;
    float* off_out = out + OUT_ELEMS;

    unsigned short* xtb  = (unsigned short*)((char*)d_ws + XT_OFF);
    float*          om   = (float*)((char*)d_ws + OM_OFF);
    unsigned short* wbf  = (unsigned short*)((char*)d_ws + WBF_OFF);
    unsigned short* womb = (unsigned short*)((char*)d_ws + WOMB_OFF);

    transpose_kernel<<<dim3(148, 4), 256, 0, stream>>>(x, weight, wom, xtb, wbf, womb);
    om_gemm_kernel  <<<dim3(144, 4), 256, 0, stream>>>(xtb, womb, om, off_out);
    dconv_kernel    <<<dim3(144, 4), 512, 0, stream>>>(xtb, wbf, bias, om, out);
}